// Round 5
// baseline (911.050 us; speedup 1.0000x reference)
//
#include <hip/hip_runtime.h>
#include <cstdint>
#include <cstddef>

// GNN (GGNN) on MI355X. Inputs fp32, output fp32; internal bf16 MFMA w/ fp32
// accum (passing since round 6: absmax 0.0117 vs threshold 0.028).
// ROUND 18: 256x256 8-phase schedule (m201 port). R14 (2-ph dbuf) and R15
// (depth-3 counted vmcnt) both null at ~22-24% MfmaUtil: counted-vmcnt is
// null on 2-phase 128-tile structures (regime gate), and the 64x32-wave
// retile made LDS reads (48KB/block-kstep) 4x the MFMA wall time. New
// structure: BM=BN=256, BK=64, 8 waves (4Mx2N), 1 block/CU, 128 KB LDS as
// 8 named 16KB half-slots (2 buf x A/B x 2 halves). Per K-tile 4 phases on
// C-quadrant path C00->C10->C11->C01 (operand reuse: ds 12/4/8/0 per phase,
// 24 b128/wave/tile = 192KB/block-tile < MFMA 2484cyc -> compute-bound).
// Each phase stages ONE half-tile of tile t+1 into the freed other buffer
// (no WAR hazard by construction); gates vmcnt(4,4,4,-) steady, (4,2,0,-)
// peeled tail, never 0 mid-loop; >=3 phases landing slack per half.
// XOR chunk swizzle (slot = logical ^ (row&7)) -> conflict-free b128 reads
// at 128B row stride, DMA-legal (pre-swizzled global source). Distinct
// named LDS arrays let alias analysis prove ds_read != gload_lds target
// (suspected R11/R14/R15 killer: compiler-injected vmcnt(0)). setprio(1)
// around MFMA clusters (T5), sched_barrier fences (rule 18).
// Retained: XCD banding, DMA w16, merged AVU3 dispatch, fused converts,
// fast sigmoid/tanh. Accumulation order per element unchanged -> absmax
// should remain 0.0117.
// Per step: T=nodes^T; [av|u3] fused; BIG: [z|r|h]pre=av@[w3w|w4w|w5w]^T
// (gates, rf=r*nodes); G4: t=rf@w5u^T; nodes=(1-z)*nodes+z*tanh(hpre+t+b5u).
// Output: nodes (fp32) ++ in_matrix (fp32 passthrough).

#define B_ 16
#define N_ 1024
#define D_ 512
#define S_ (B_ * N_)      // 16384
#define TWO_D 1024

typedef __attribute__((ext_vector_type(8))) short short8;
typedef __attribute__((ext_vector_type(4))) short s16x4;
typedef __attribute__((ext_vector_type(4))) float f32x4;

#define EPI_AVU3 0
#define EPI_BIG  2
#define EPI_G4   3

__device__ __forceinline__ float bf2f(short u) {
  union { unsigned int i; float f; } v;
  v.i = ((unsigned int)(unsigned short)u) << 16;
  return v.f;
}
__device__ __forceinline__ short f2bf(float f) {
  union { float f; unsigned int i; } v;
  v.f = f;
  unsigned int x = v.i;
  unsigned int r = (x + 0x7fffu + ((x >> 16) & 1u)) >> 16;  // RTNE
  return (short)(unsigned short)r;
}
__device__ __forceinline__ float fast_sigmoid(float x) {
  return __builtin_amdgcn_rcpf(1.f + __expf(-x));
}
__device__ __forceinline__ float fast_tanh(float x) {
  const float t = __expf(-2.f * fabsf(x));
  const float th = (1.f - t) * __builtin_amdgcn_rcpf(1.f + t);
  return __builtin_copysignf(th, x);
}

// Async global->LDS DMA, 16 bytes/lane; LDS dest = wave-uniform base+lane*16.
__device__ __forceinline__ void gload16(const void* g, void* l) {
  __builtin_amdgcn_global_load_lds(
      (__attribute__((address_space(1))) void*)g,
      (__attribute__((address_space(3))) void*)l, 16, 0, 0);
}

#define WAITV_IMM(N) asm volatile("s_waitcnt vmcnt(" #N ")" ::: "memory")
#define WAITV(N) WAITV_IMM(N)
#define LGKM0 asm volatile("s_waitcnt lgkmcnt(0)" ::: "memory")
#define BAR() __builtin_amdgcn_s_barrier()
#define SCHEDB() __builtin_amdgcn_sched_barrier(0)
#define PRIO1 __builtin_amdgcn_s_setprio(1)
#define PRIO0 __builtin_amdgcn_s_setprio(0)

// C[M,Nc] = A[M,K] * Bw[Nc,K]^T, bf16 in memory, fp32 accum.
// 256x256 tile, BK=64, 512 threads = 8 waves (4M x 2N within each 128x128
// quadrant; per wave 32 rows x 64 cols per quadrant-phase).
// MFMA frag layouts (m89/m91): A/B: row/col = lane&15, k = (lane>>4)*8 + j;
// C/D: col = lane&15, row = (lane>>4)*4 + r.
// LDS half-slot = 128 rows x 64 k bf16 = 16 KB. Physical 16B chunk slot =
// (logical chunk) ^ (row&7): conflict-free ds_read_b128 (16-lane group's
// rows cover all 8 slots twice -> 2/bank-quad) AND DMA-legal lane-linear
// dest with pre-swizzled global source (thread tid: row=tid>>3, phys slot
// tid&7, logical chunk = (tid&7)^((tid>>3)&7)).
// EPI_AVU3: blockIdx.z < 2C -> adjacency slice (batch z>>1, inM/outM by z&1,
// K=N_); z >= 2C -> U3 GEMM for batch z-2C (K=D_).
template <int EPI>
__global__ __launch_bounds__(512, 2) void gemm_nt(
    const short* A, const short* A2, int lda,
    const short* Bw, const short* Bw2, const short* Bw3, int ldb, int Kin,
    const float* bias0, const float* bias1, const float* bias2,
    const short* u3, const short* fcur,   // may alias out0 (in-place G4)
    const short* hvp, const short* zvp,
    short* out0, short* out1, short* out2,
    float* outf, int twoC) {               // EPI_G4 final step: fp32 d_out
  // 8 named 16 KB half-slots: s{A,B}{buf}{half}. 128 KB total.
  __shared__ __align__(16) short sA00[8192];
  __shared__ __align__(16) short sA01[8192];
  __shared__ __align__(16) short sB00[8192];
  __shared__ __align__(16) short sB01[8192];
  __shared__ __align__(16) short sA10[8192];
  __shared__ __align__(16) short sA11[8192];
  __shared__ __align__(16) short sB10[8192];
  __shared__ __align__(16) short sB11[8192];

  const int tid = threadIdx.x;
  const int lane = tid & 63;
  const int wave = tid >> 6;          // 0..7
  const int wm = wave & 3;            // 32-row band within 128-row quadrant
  const int wn = wave >> 2;           // 64-col band within 128-col quadrant

  // ---- XCD-aware swizzle (assumes linear-block -> XCD = id % 8) ----
  int bx = blockIdx.x, by = blockIdx.y, bz = blockIdx.z;
  if constexpr (EPI == EPI_AVU3) {
    const int total = gridDim.x * gridDim.y * gridDim.z;  // 24C, %8==0
    const int id = (bz * gridDim.y + by) * gridDim.x + bx;
    if ((total & 7) == 0) {
      const int a = id & 7, m = id >> 3;
      const int l = a * (total >> 3) + m;
      bx = l & 1;                 // gx = 2
      by = (l >> 1) & 3;          // gy = 4
      bz = l >> 3;
    }
  } else {
    const int gx = gridDim.x, gy = gridDim.y;
    if ((gy & 7) == 0) {
      const int id = by * gx + bx;
      const int a = id & 7;
      const int m = id >> 3;
      const int per = gy >> 3;
      by = a * per + m / gx;
      bx = m % gx;
    }
  }

  int m0 = by * 256;
  const int n0 = bx * 256;
  int K = Kin;

  const short* Aeff = A;
  const short* Beff = Bw;
  int lda_e = lda, ldb_e = ldb;
  int nb0 = n0;
  bool isU3 = false;
  int b_ = 0, j_ = 0;
  if constexpr (EPI == EPI_AVU3) {
    if (bz < twoC) {               // adjacency slice
      b_ = bz >> 1;
      j_ = bz & 1;
      Aeff = j_ ? A2 : A;                              // inM / outM
      Beff = Bw + (size_t)b_ * ((size_t)D_ * N_);      // T for batch b_
      lda_e = N_; ldb_e = N_; K = N_;
    } else {                       // U3 slice for batch bz-twoC
      isU3 = true;
      const int b = bz - twoC;
      Aeff = u3 /*nodes base*/ + (size_t)b * N_ * D_;
      Beff = Bw3 /*w3u*/;
      lda_e = D_; ldb_e = D_; K = D_;
      b_ = b;
    }
  } else if constexpr (EPI == EPI_BIG) {
    if (n0 < 512) { Beff = Bw; nb0 = n0; }
    else if (n0 < 1024) { Beff = Bw2; nb0 = n0 - 512; }
    else { Beff = Bw3; nb0 = n0 - 1024; }
  }

  f32x4 acc[2][2][2][4];   // [R quad][Cq quad][fm][fn]
#pragma unroll
  for (int R = 0; R < 2; R++)
#pragma unroll
    for (int Cq = 0; Cq < 2; Cq++)
#pragma unroll
      for (int fm = 0; fm < 2; fm++)
#pragma unroll
        for (int fn = 0; fn < 4; fn++)
          acc[R][Cq][fm][fn] = (f32x4){0.f, 0.f, 0.f, 0.f};

  // ---- LDS frag read offsets (conflict-free XOR chunk swizzle) ----
  const int lm = lane & 15;
  const int qq = lane >> 4;
  int offA[2][2], offB[4][2];
#pragma unroll
  for (int fm = 0; fm < 2; fm++)
#pragma unroll
    for (int ks = 0; ks < 2; ks++) {
      const int rw = wm * 32 + fm * 16 + lm;
      offA[fm][ks] = rw * 128 + (((ks * 4 + qq) ^ (lm & 7)) << 4);
    }
#pragma unroll
  for (int fn = 0; fn < 4; fn++)
#pragma unroll
    for (int ks = 0; ks < 2; ks++) {
      const int rw = wn * 64 + fn * 16 + lm;
      offB[fn][ks] = rw * 128 + (((ks * 4 + qq) ^ (lm & 7)) << 4);
    }

  // ---- DMA: thread tid stages row (call*64 + tid>>3), phys slot tid&7,
  //      logical chunk (tid&7)^((tid>>3)&7). 2 calls per 16 KB half. ----
  const int rr = tid >> 3;
  const int qv = ((tid & 7) ^ (rr & 7)) * 8;
  const short* pA00 = Aeff + (size_t)(m0 + rr) * lda_e + qv;        // h0 c0
  const short* pA01 = Aeff + (size_t)(m0 + 64 + rr) * lda_e + qv;   // h0 c1
  const short* pA10 = Aeff + (size_t)(m0 + 128 + rr) * lda_e + qv;  // h1 c0
  const short* pA11 = Aeff + (size_t)(m0 + 192 + rr) * lda_e + qv;  // h1 c1
  const short* pB00 = Beff + (size_t)(nb0 + rr) * ldb_e + qv;
  const short* pB01 = Beff + (size_t)(nb0 + 64 + rr) * ldb_e + qv;
  const short* pB10 = Beff + (size_t)(nb0 + 128 + rr) * ldb_e + qv;
  const short* pB11 = Beff + (size_t)(nb0 + 192 + rr) * ldb_e + qv;
  const int dst0 = tid * 16;          // call 0 LDS byte offset
  const int dst1 = 8192 + tid * 16;   // call 1

#define STAGE_A0(ARR, kn) do { \
    gload16(pA00 + (size_t)(kn) * 64, (char*)ARR + dst0); \
    gload16(pA01 + (size_t)(kn) * 64, (char*)ARR + dst1); } while (0)
#define STAGE_A1(ARR, kn) do { \
    gload16(pA10 + (size_t)(kn) * 64, (char*)ARR + dst0); \
    gload16(pA11 + (size_t)(kn) * 64, (char*)ARR + dst1); } while (0)
#define STAGE_B0(ARR, kn) do { \
    gload16(pB00 + (size_t)(kn) * 64, (char*)ARR + dst0); \
    gload16(pB01 + (size_t)(kn) * 64, (char*)ARR + dst1); } while (0)
#define STAGE_B1(ARR, kn) do { \
    gload16(pB10 + (size_t)(kn) * 64, (char*)ARR + dst0); \
    gload16(pB11 + (size_t)(kn) * 64, (char*)ARR + dst1); } while (0)

  short8 a0f[2][2], a1f[2][2], bfrag[4][2];

#define READ_A(dst, ARR) \
  _Pragma("unroll") for (int fm = 0; fm < 2; fm++) \
  _Pragma("unroll") for (int ks = 0; ks < 2; ks++) \
      dst[fm][ks] = *(const short8*)((const char*)ARR + offA[fm][ks]);
#define READ_B(ARR) \
  _Pragma("unroll") for (int fn = 0; fn < 4; fn++) \
  _Pragma("unroll") for (int ks = 0; ks < 2; ks++) \
      bfrag[fn][ks] = *(const short8*)((const char*)ARR + offB[fn][ks]);
#define PHASE_MFMA(R, Cq, AF) \
  _Pragma("unroll") for (int fm = 0; fm < 2; fm++) \
  _Pragma("unroll") for (int fn = 0; fn < 4; fn++) \
  _Pragma("unroll") for (int ks = 0; ks < 2; ks++) \
      acc[R][Cq][fm][fn] = __builtin_amdgcn_mfma_f32_16x16x32_bf16( \
          AF[fm][ks], bfrag[fn][ks], acc[R][Cq][fm][fn], 0, 0, 0);

  // Per-tile body: compute tile in c-buffer arrays, stage tile kn into
  // o-buffer arrays (one half per phase, order A0,B0,A1,B1).
  // Quadrant path C00 -> C10 -> C11 -> C01; ds reads 12/4/8/0.
#define TILE_BODY(cA0_, cA1_, cB0_, cB1_, oA0_, oA1_, oB0_, oB1_, kn, DS, \
                  G0_, G1_, G2_) \
  do { \
    WAITV(G0_); BAR(); SCHEDB(); \
    READ_A(a0f, cA0_); READ_B(cB0_); \
    if (DS) STAGE_A0(oA0_, kn); \
    LGKM0; SCHEDB(); \
    PRIO1; PHASE_MFMA(0, 0, a0f); PRIO0; \
    WAITV(G1_); BAR(); SCHEDB(); \
    READ_A(a1f, cA1_); \
    if (DS) STAGE_B0(oB0_, kn); \
    LGKM0; SCHEDB(); \
    PRIO1; PHASE_MFMA(1, 0, a1f); PRIO0; \
    WAITV(G2_); BAR(); SCHEDB(); \
    READ_B(cB1_); \
    if (DS) STAGE_A1(oA1_, kn); \
    LGKM0; SCHEDB(); \
    PRIO1; PHASE_MFMA(1, 1, a1f); PRIO0; \
    if (DS) STAGE_B1(oB1_, kn); \
    PRIO1; PHASE_MFMA(0, 1, a0f); PRIO0; \
  } while (0)

  const int KT = K >> 6;    // K-tiles of 64; K in {512,1024} -> KT even >= 8

  // prologue: stage tile 0 into buf0, order A0,B0,A1,B1 (8 loads in flight)
  STAGE_A0(sA00, 0);
  STAGE_B0(sB00, 0);
  STAGE_A1(sA01, 0);
  STAGE_B1(sB01, 0);

  int t = 0;
  for (; t + 2 < KT; t += 2) {
    TILE_BODY(sA00, sA01, sB00, sB01, sA10, sA11, sB10, sB11, t + 1, 1,
              4, 4, 4);
    TILE_BODY(sA10, sA11, sB10, sB11, sA00, sA01, sB00, sB01, t + 2, 1,
              4, 4, 4);
  }
  // t == KT-2 (even): compute KT-2 from buf0, stage KT-1 into buf1
  TILE_BODY(sA00, sA01, sB00, sB01, sA10, sA11, sB10, sB11, KT - 1, 1,
            4, 4, 4);
  // tail: tile KT-1 from buf1, no staging; gates 4,2,0
  TILE_BODY(sA10, sA11, sB10, sB11, sA00, sA01, sB00, sB01, 0, 0,
            4, 2, 0);

#undef TILE_BODY
#undef PHASE_MFMA
#undef READ_A
#undef READ_B
#undef STAGE_A0
#undef STAGE_A1
#undef STAGE_B0
#undef STAGE_B1

  // ---- epilogue ----
  const int r4 = lane >> 4;
#pragma unroll
  for (int R = 0; R < 2; R++) {
#pragma unroll
    for (int Cq = 0; Cq < 2; Cq++) {
#pragma unroll
      for (int fm = 0; fm < 2; fm++) {
#pragma unroll
        for (int fn = 0; fn < 4; fn++) {
#pragma unroll
          for (int r = 0; r < 4; r++) {
            const int grow = m0 + R * 128 + wm * 32 + fm * 16 + r4 * 4 + r;
            const int gcol = n0 + Cq * 128 + wn * 64 + fn * 16 + lm;
            const float v = acc[R][Cq][fm][fn][r];
            if constexpr (EPI == EPI_AVU3) {
              if (!isU3) {
                out0[((size_t)(b_ * N_ + grow)) * TWO_D + j_ * D_ + gcol] =
                    f2bf(v);
              } else {
                out1[((size_t)(b_ * N_ + grow)) * D_ + gcol] =
                    f2bf(v + bias0[gcol]);
              }
            } else if constexpr (EPI == EPI_BIG) {
              if (gcol < 512) {
                const size_t sidx = (size_t)grow * D_ + gcol;
                const float x = v + bias0[gcol] + bf2f(u3[sidx]);
                out0[sidx] = f2bf(fast_sigmoid(x));
              } else if (gcol < 1024) {
                const int e = gcol - 512;
                const size_t sidx = (size_t)grow * D_ + e;
                const float x = v + bias1[e] + bf2f(u3[sidx]);
                out1[sidx] = f2bf(fast_sigmoid(x) * bf2f(fcur[sidx]));
              } else {
                const int e = gcol - 1024;
                const size_t sidx = (size_t)grow * D_ + e;
                out2[sidx] = f2bf(v + bias2[e]);
              }
            } else {  // EPI_G4 (in-place: same thread reads then writes sidx)
              const size_t sidx = (size_t)grow * D_ + gcol;
              const float x = bf2f(hvp[sidx]) + v + bias0[gcol];
              const float hv = fast_tanh(x);
              const float z = bf2f(zvp[sidx]);
              const float f = bf2f(fcur[sidx]);
              const float res = (1.f - z) * f + z * hv;
              if (outf) outf[sidx] = res;      // final step: fp32 to d_out
              else out0[sidx] = f2bf(res);     // intermediate: bf16 update
            }
          }
        }
      }
    }
  }
}

// bf16 [C][N][D] -> bf16 [C][D][N] transpose.
__global__ void transpose_bnd(const short* __restrict__ in,
                              short* __restrict__ out) {
  __shared__ short tile[32][33];
  const int b = blockIdx.z;
  const int n0 = blockIdx.y * 32;
  const int d0 = blockIdx.x * 32;
  const int tx = threadIdx.x, ty = threadIdx.y;
  const short* ip = in + (size_t)b * N_ * D_;
  short* op = out + (size_t)b * N_ * D_;
#pragma unroll
  for (int yy = ty; yy < 32; yy += 8)
    tile[yy][tx] = ip[(size_t)(n0 + yy) * D_ + d0 + tx];
  __syncthreads();
#pragma unroll
  for (int yy = ty; yy < 32; yy += 8)
    op[(size_t)(d0 + yy) * N_ + n0 + tx] = tile[tx][yy];
}

// One-shot segmented fp32->bf16 convert (8 jobs, grid-stride over v4 elems).
struct CvtJobs {
  const float* src[8];
  short* dst[8];
  int end4[8];
  int tot4;
};
__global__ void cvt_all(CvtJobs j) {
  for (int idx = blockIdx.x * 256 + threadIdx.x; idx < j.tot4;
       idx += gridDim.x * 256) {
    int k = 0, start = 0;
#pragma unroll
    for (int t = 0; t < 8; t++) {
      if (idx >= j.end4[t]) { k = t + 1; start = j.end4[t]; }
    }
    const int rel = idx - start;
    const f32x4 v = ((const f32x4*)j.src[k])[rel];
    s16x4 o;
#pragma unroll
    for (int r = 0; r < 4; r++) o[r] = f2bf(v[r]);
    ((s16x4*)j.dst[k])[rel] = o;
  }
}

extern "C" void kernel_launch(void* const* d_in, const int* in_sizes, int n_in,
                              void* d_out, int out_size, void* d_ws,
                              size_t ws_size, hipStream_t stream) {
  const float* x = (const float*)d_in[0];
  const float* inM = (const float*)d_in[1];
  const float* outM = (const float*)d_in[2];
  const float* w3w = (const float*)d_in[3];
  const float* b3w = (const float*)d_in[4];
  const float* w3u = (const float*)d_in[5];
  const float* b3u = (const float*)d_in[6];
  const float* w4w = (const float*)d_in[7];
  const float* b4w = (const float*)d_in[8];
  const float* w5w = (const float*)d_in[9];
  const float* b5w = (const float*)d_in[10];
  const float* w5u = (const float*)d_in[11];
  const float* b5u = (const float*)d_in[12];
  float* outF = (float*)d_out;   // fp32 output: nodes [S_,D_] ++ in_matrix

  char* ws = (char*)d_ws;
  size_t off = 0;
  auto alloc = [&](size_t elems) {
    short* p = (short*)(ws + off);
    off = (off + elems * 2 + 255) & ~(size_t)255;
    return p;
  };
  short* nodes = alloc((size_t)S_ * D_);           // bf16 recursion state
  short* inMb = alloc((size_t)N_ * N_);
  short* outMb = alloc((size_t)N_ * N_);
  short* w3wb = alloc((size_t)512 * 1024);
  short* w4wb = alloc((size_t)512 * 1024);
  short* w5wb = alloc((size_t)512 * 1024);
  short* w3ub = alloc((size_t)D_ * D_);
  short* w5ub = alloc((size_t)D_ * D_);
  const size_t fixed = off;

  // chunk size C: per-chunk scratch = T+av+u3+zv+rf+hvp = 7*C*N*D bf16
  int C = 1;
  for (int c = 16; c >= 1; c >>= 1) {
    const size_t need = fixed + (size_t)7 * c * N_ * D_ * 2 + 8 * 256;
    if (need <= ws_size) { C = c; break; }
  }
  short* T = alloc((size_t)C * D_ * N_);
  short* av = alloc((size_t)C * N_ * TWO_D);
  short* u3 = alloc((size_t)C * N_ * D_);
  short* zv = alloc((size_t)C * N_ * D_);
  short* rf = alloc((size_t)C * N_ * D_);
  short* hvp = alloc((size_t)C * N_ * D_);

  // --- one fused convert launch: fp32 -> bf16 working set ---
  CvtJobs cj;
  const int xs4 = S_ * D_ / 4, nn4 = N_ * N_ / 4;
  const int dd4 = D_ * D_ / 4, wd4 = 512 * 1024 / 4;
  const float* srcs[8] = {x, inM, outM, w3w, w4w, w5w, w3u, w5u};
  short* dsts[8] = {nodes, inMb, outMb, w3wb, w4wb, w5wb, w3ub, w5ub};
  const int lens[8] = {xs4, nn4, nn4, wd4, wd4, wd4, dd4, dd4};
  int cum = 0;
  for (int i = 0; i < 8; i++) {
    cj.src[i] = srcs[i];
    cj.dst[i] = dsts[i];
    cum += lens[i];
    cj.end4[i] = cum;
  }
  cj.tot4 = cum;
  cvt_all<<<1536, 256, 0, stream>>>(cj);
  // output 1: in_matrix passthrough (fp32 bit copy)
  hipMemcpyAsync(outF + (size_t)S_ * D_, inM, (size_t)N_ * N_ * 4,
                 hipMemcpyDeviceToDevice, stream);

  const dim3 tb32(32, 8);
  const dim3 tg(D_ / 32, N_ / 32, C);
  const dim3 g_avu3(D_ / 256, N_ / 256, 3 * C);     // (2,4,3C): AV + U3
  const dim3 g_d(D_ / 256, C * N_ / 256, 1);        // (2,4C)
  const dim3 g_big(1536 / 256, C * N_ / 256, 1);    // (6,4C)

  const int nchunks = B_ / C;
  for (int c = 0; c < nchunks; ++c) {
    short* nodes_c = nodes + (size_t)c * C * N_ * D_;
    float* outF_c = outF + (size_t)c * C * N_ * D_;
    for (int step = 0; step < 3; ++step) {
      transpose_bnd<<<tg, tb32, 0, stream>>>(nodes_c, T);
      gemm_nt<EPI_AVU3><<<g_avu3, 512, 0, stream>>>(
          inMb, outMb, N_, T, nullptr, w3ub, N_, N_, b3u, nullptr, nullptr,
          nodes_c, nullptr, nullptr, nullptr, av, u3, nullptr, nullptr,
          2 * C);
      gemm_nt<EPI_BIG><<<g_big, 512, 0, stream>>>(
          av, nullptr, TWO_D, w3wb, w4wb, w5wb, TWO_D, TWO_D, b3w, b4w, b5w,
          u3, nodes_c, nullptr, nullptr, zv, rf, hvp, nullptr, 0);
      float* outf = (step == 2) ? outF_c : nullptr;
      gemm_nt<EPI_G4><<<g_d, 512, 0, stream>>>(
          rf, nullptr, D_, w5ub, nullptr, nullptr, D_, D_, b5u, nullptr,
          nullptr, nullptr, nodes_c, hvp, zv, nodes_c, nullptr, nullptr,
          outf, 0);
    }
  }
}